// Round 1
// baseline (287.165 us; speedup 1.0000x reference)
//
#include <hip/hip_runtime.h>
#include <hip/hip_bf16.h>
#include <stdint.h>

#define B_ 16
#define C_ 256
#define O_ 256
#define H_ 64
#define W_ 64
#define HP 66
#define WP 66
#define HIDDEN 65
#define TEMP 34.0f

#define BM 128
#define BN 128
#define BK 32
#define LDK 40   // LDS row stride (ushorts): 32 + 8 pad -> 2-way bank aliasing (free)

typedef __bf16 bf16x8 __attribute__((ext_vector_type(8)));
typedef float floatx4 __attribute__((ext_vector_type(4)));

__device__ __forceinline__ unsigned short f2bf(float f) {
    union { float f; uint32_t u; } v; v.f = f;
    uint32_t u = v.u;
    uint32_t r = (u + 0x7FFFu + ((u >> 16) & 1u)) >> 16;
    return (unsigned short)r;
}

// ---------------------------------------------------------------------------
// Kernel 1: zero-padded NCHW->NHWC bf16 transpose of x, fused with pooling sums.
// Grid: 16*66 blocks (one per (b, padded-row)), 256 threads.
// xp layout: [b][hp][wp][c], hp,wp in [0,66), border rows/cols are zero.
// ---------------------------------------------------------------------------
__global__ void pad_pool_kernel(const float* __restrict__ x,
                                unsigned short* __restrict__ xp,
                                float* __restrict__ pooled) {
    int b  = blockIdx.x / HP;
    int hp = blockIdx.x % HP;
    unsigned short* xpb = xp + ((size_t)(b * HP + hp)) * WP * C_;
    int tid = threadIdx.x;

    if (hp == 0 || hp == HP - 1) {
        for (int i = tid; i < WP * C_; i += 256) xpb[i] = 0;
        return;
    }
    int h = hp - 1;

    __shared__ unsigned short ld[256 * 66];   // [c][w], stride 66 (bank-friendly)

    int w  = tid & 63;
    int cq = tid >> 6;
    const float* xb = x + (size_t)b * C_ * H_ * W_ + (size_t)h * W_;
    #pragma unroll 4
    for (int i = 0; i < 64; i++) {
        int c = i * 4 + cq;
        float v = xb[(size_t)c * H_ * W_ + w];
        ld[c * 66 + w] = f2bf(v);
    }
    __syncthreads();

    // zero the left/right padding columns
    xpb[0 * C_ + tid] = 0;                 // wp = 0
    xpb[65 * C_ + tid] = 0;                // wp = 65

    // transposed write: for each w, 256 contiguous channels
    #pragma unroll 4
    for (int w2 = 0; w2 < 64; w2++) {
        xpb[(size_t)(w2 + 1) * C_ + tid] = ld[tid * 66 + w2];
    }

    // pooling: thread tid owns channel c = tid, sum its 64 pixels of this row
    float s = 0.f;
    #pragma unroll 8
    for (int w2 = 0; w2 < 64; w2++) {
        union { uint32_t u; float f; } vv;
        vv.u = ((uint32_t)ld[tid * 66 + w2]) << 16;
        s += vv.f;
    }
    atomicAdd(&pooled[b * C_ + tid], s);
}

// ---------------------------------------------------------------------------
// Kernel 2: attention MLP + softmax. Single block.
// ---------------------------------------------------------------------------
__global__ void att_kernel(const float* __restrict__ pooled,
                           const float* __restrict__ w1,
                           const float* __restrict__ w2,
                           const float* __restrict__ b2,
                           float* __restrict__ att) {
    __shared__ float psh[B_ * C_];
    __shared__ float hsh[B_ * HIDDEN];
    int tid = threadIdx.x;
    for (int i = tid; i < B_ * C_; i += 256) psh[i] = pooled[i] * (1.0f / (H_ * W_));
    __syncthreads();
    for (int i = tid; i < B_ * HIDDEN; i += 256) {
        int b = i / HIDDEN, j = i % HIDDEN;
        float s = 0.f;
        for (int c = 0; c < C_; c++) s += psh[b * C_ + c] * w1[j * C_ + c];
        hsh[i] = fmaxf(s, 0.f);
    }
    __syncthreads();
    if (tid < B_) {
        float lg[4];
        float mx = -1e30f;
        for (int k = 0; k < 4; k++) {
            float s = b2[k];
            for (int j = 0; j < HIDDEN; j++) s += hsh[tid * HIDDEN + j] * w2[k * HIDDEN + j];
            lg[k] = s / TEMP;
            mx = fmaxf(mx, lg[k]);
        }
        float den = 0.f;
        for (int k = 0; k < 4; k++) { lg[k] = expf(lg[k] - mx); den += lg[k]; }
        for (int k = 0; k < 4; k++) att[tid * 4 + k] = lg[k] / den;
    }
}

// ---------------------------------------------------------------------------
// Kernel 3: aggregate per-sample weights into bf16, layout [b][tap][o][c]
// (c contiguous => K-contiguous A rows for the GEMM).
// Grid: 256 blocks (one per o), 256 threads (one per c).
// ---------------------------------------------------------------------------
__global__ void agg_kernel(const float* __restrict__ weight,
                           const float* __restrict__ att,
                           unsigned short* __restrict__ aggw) {
    int o = blockIdx.x;
    int c = threadIdx.x;
    __shared__ float a_sh[B_ * 4];
    if (c < B_ * 4) a_sh[c] = att[c];
    __syncthreads();

    float wv[4][9];
    #pragma unroll
    for (int k = 0; k < 4; k++) {
        const float* wp = weight + (((size_t)k * O_ + o) * C_ + c) * 9;
        #pragma unroll
        for (int t = 0; t < 9; t++) wv[k][t] = wp[t];
    }
    for (int b = 0; b < B_; b++) {
        float a0 = a_sh[b * 4 + 0], a1 = a_sh[b * 4 + 1];
        float a2 = a_sh[b * 4 + 2], a3 = a_sh[b * 4 + 3];
        #pragma unroll
        for (int t = 0; t < 9; t++) {
            float s = a0 * wv[0][t] + a1 * wv[1][t] + a2 * wv[2][t] + a3 * wv[3][t];
            aggw[(((size_t)b * 9 + t) * O_ + o) * C_ + c] = f2bf(s);
        }
    }
}

// ---------------------------------------------------------------------------
// Kernel 4: the conv as 9 shifted GEMMs. Per block: one 128x128 tile of
// out[b] (M = out-ch, N = pixels). K-loop: 9 taps x (256 c / BK=32).
// A tile: aggw[b][t][o][c]  (rows o, K-contig)
// B tile: xp[b][h+ty][w+tx][c] (rows pixel, K-contig, padding handles edges)
// ---------------------------------------------------------------------------
__global__ __launch_bounds__(256) void conv_kernel(
    const unsigned short* __restrict__ xp,    // [B][66][66][C] bf16
    const unsigned short* __restrict__ aggw,  // [B][9][O][C]  bf16
    float* __restrict__ out)                  // [B][O][4096]  f32
{
    __shared__ unsigned short As[BM * LDK];
    __shared__ unsigned short Bs[BN * LDK];

    int bid = blockIdx.x;
    int b  = bid >> 6;      // 64 blocks per sample
    int r  = bid & 63;
    int mt = r >> 5;        // 0..1  (o-tile)
    int nt = r & 31;        // 0..31 (pixel-tile)
    int tid = threadIdx.x;
    int h0 = nt * 2;        // pixel base nt*128 -> image rows h0, h0+1

    // staging: each thread moves 2x16B for A and 2x16B for B per K-chunk
    int srow = tid >> 2;          // 0..63
    int scc  = (tid & 3) * 8;     // 0,8,16,24 (ushort offset)

    // MFMA fragment indexing
    int wave = tid >> 6;
    int lane = tid & 63;
    int wr = (wave >> 1) * 64;    // wave M offset
    int wc = (wave & 1) * 64;     // wave N offset
    int fm = lane & 15;
    int q  = lane >> 4;

    // LDS element offsets for fragment reads (loop-invariant)
    int aOff[4], bOff[4];
    #pragma unroll
    for (int i = 0; i < 4; i++) {
        aOff[i] = (wr + i * 16 + fm) * LDK + q * 8;
        bOff[i] = (wc + i * 16 + fm) * LDK + q * 8;
    }
    int asW0 = srow * LDK + scc;
    int asW1 = (srow + 64) * LDK + scc;

    floatx4 acc[4][4] = {};

    const unsigned short* aggb = aggw + (size_t)b * 9 * O_ * C_ + (size_t)mt * BM * C_;
    const unsigned short* xpb  = xp + (size_t)b * HP * WP * C_;

    for (int t = 0; t < 9; t++) {
        int ty = t / 3, tx = t % 3;
        const unsigned short* a0 = aggb + (size_t)t * O_ * C_ + (size_t)srow * C_ + scc;
        const unsigned short* a1 = a0 + (size_t)64 * C_;
        // pixel p0 = srow (row h0), p1 = srow+64 (row h0+1)
        const unsigned short* b0 = xpb + ((size_t)(h0 + 0 + ty) * WP + srow + tx) * C_ + scc;
        const unsigned short* b1 = xpb + ((size_t)(h0 + 1 + ty) * WP + srow + tx) * C_ + scc;

        for (int c0 = 0; c0 < C_; c0 += BK) {
            *(uint4*)(&As[asW0]) = *(const uint4*)(a0 + c0);
            *(uint4*)(&As[asW1]) = *(const uint4*)(a1 + c0);
            *(uint4*)(&Bs[asW0]) = *(const uint4*)(b0 + c0);
            *(uint4*)(&Bs[asW1]) = *(const uint4*)(b1 + c0);
            __syncthreads();

            bf16x8 af[4], bfr[4];
            #pragma unroll
            for (int i = 0; i < 4; i++) {
                af[i]  = *(const bf16x8*)(&As[aOff[i]]);
                bfr[i] = *(const bf16x8*)(&Bs[bOff[i]]);
            }
            #pragma unroll
            for (int i = 0; i < 4; i++)
                #pragma unroll
                for (int j = 0; j < 4; j++)
                    acc[i][j] = __builtin_amdgcn_mfma_f32_16x16x32_bf16(af[i], bfr[j], acc[i][j], 0, 0, 0);
            __syncthreads();
        }
    }

    // epilogue: C/D layout col = lane&15 (n), row = q*4 + reg (m)
    float* outb = out + ((size_t)b * O_ + mt * BM) * (H_ * W_) + (size_t)nt * BN;
    #pragma unroll
    for (int i = 0; i < 4; i++) {
        #pragma unroll
        for (int j = 0; j < 4; j++) {
            #pragma unroll
            for (int rr = 0; rr < 4; rr++) {
                int m = wr + i * 16 + q * 4 + rr;
                int n = wc + j * 16 + fm;
                outb[(size_t)m * (H_ * W_) + n] = acc[i][j][rr];
            }
        }
    }
}

// ---------------------------------------------------------------------------
extern "C" void kernel_launch(void* const* d_in, const int* in_sizes, int n_in,
                              void* d_out, int out_size, void* d_ws, size_t ws_size,
                              hipStream_t stream) {
    const float* x      = (const float*)d_in[0];
    const float* weight = (const float*)d_in[1];
    const float* att_w1 = (const float*)d_in[2];
    const float* att_w2 = (const float*)d_in[3];
    const float* att_b2 = (const float*)d_in[4];
    float* out = (float*)d_out;

    char* ws = (char*)d_ws;
    float* pooled        = (float*)ws;                          // 16 KiB
    float* att           = (float*)(ws + 16384);                // 256 B
    unsigned short* aggw = (unsigned short*)(ws + 32768);       // 16*9*256*256*2 = 18,874,368 B
    unsigned short* xp   = (unsigned short*)(ws + 32768 + 18874368); // 16*66*66*256*2 = 35,684,352 B

    hipMemsetAsync(pooled, 0, B_ * C_ * sizeof(float), stream);
    pad_pool_kernel<<<B_ * HP, 256, 0, stream>>>(x, xp, pooled);
    att_kernel<<<1, 256, 0, stream>>>(pooled, att_w1, att_w2, att_b2, att);
    agg_kernel<<<O_, 256, 0, stream>>>(weight, att, aggw);
    conv_kernel<<<B_ * 64, 256, 0, stream>>>(xp, aggw, out);
}